// Round 10
// baseline (310.231 us; speedup 1.0000x reference)
//
#include <hip/hip_runtime.h>
#include <stdint.h>

#define HIDDEN 512
#define NLAYERS 3
#define KNN 8
#define CAP 64
#define EPSV 1e-5f
#define GRID 32
#define NCELL (GRID * GRID)

typedef unsigned long long u64;
typedef __attribute__((ext_vector_type(8))) short short8;   // 8 bf16 = 4 VGPRs
typedef __attribute__((ext_vector_type(4))) float f32x4;    // MFMA acc

// async global->LDS DMA, 16 B/lane; LDS dest = wave-uniform base + lane*16
#define GLL16(gp, lp)                                                         \
  __builtin_amdgcn_global_load_lds(                                           \
      (const __attribute__((address_space(1))) unsigned int*)(gp),            \
      (__attribute__((address_space(3))) unsigned int*)(lp), 16, 0, 0)

__device__ inline unsigned short f2bf(float x) {  // RNE fp32 -> bf16 bits
  union { float f; unsigned u; } v; v.f = x;
  unsigned r = v.u + 0x7FFFu + ((v.u >> 16) & 1u);
  return (unsigned short)(r >> 16);
}
__device__ inline float bf2f(unsigned short u) {
  return __uint_as_float((unsigned)u << 16);
}

// ---------------------------------------------------------------------------
// Grid build: one 1024-thread block per batch. Counting sort into 32x32 cells.
// ---------------------------------------------------------------------------
__global__ __launch_bounds__(1024) void grid_build_kernel(
    const float2* __restrict__ coords, int* __restrict__ cell_start,
    float2* __restrict__ scoord, int* __restrict__ sorig, int N) {
  __shared__ int hist[NCELL];
  __shared__ int offs[NCELL];
  int b = blockIdx.x;
  int t = threadIdx.x;
  hist[t] = 0;
  __syncthreads();
  const float2* cb = coords + (size_t)b * N;
  int mycell[4];
#pragma unroll
  for (int r = 0; r < 4; ++r) {
    int i = t + r * 1024;
    float2 c = cb[i];
    int cx = (int)(c.x * GRID); cx = cx < 0 ? 0 : (cx > GRID - 1 ? GRID - 1 : cx);
    int cy = (int)(c.y * GRID); cy = cy < 0 ? 0 : (cy > GRID - 1 ? GRID - 1 : cy);
    mycell[r] = cy * GRID + cx;
    atomicAdd(&hist[mycell[r]], 1);
  }
  __syncthreads();
  int v = hist[t];
  offs[t] = v;
  __syncthreads();
  for (int d = 1; d < NCELL; d <<= 1) {
    int add = (t >= d) ? offs[t - d] : 0;
    __syncthreads();
    offs[t] += add;
    __syncthreads();
  }
  int excl = offs[t] - v;
  cell_start[(size_t)b * (NCELL + 1) + t] = excl;
  if (t == 0) cell_start[(size_t)b * (NCELL + 1) + NCELL] = N;
  hist[t] = excl;
  __syncthreads();
#pragma unroll
  for (int r = 0; r < 4; ++r) {
    int i = t + r * 1024;
    int pos = atomicAdd(&hist[mycell[r]], 1);
    scoord[(size_t)b * N + pos] = cb[i];
    sorig[(size_t)b * N + pos] = i;
  }
}

// ---------------------------------------------------------------------------
// Gang-of-8 grid kNN (checker-bit-exact d2) with fused reverse-adjacency.
// ---------------------------------------------------------------------------
__global__ __launch_bounds__(256) void knn_grid_kernel(
    const int* __restrict__ cell_start, const float2* __restrict__ scoord,
    const int* __restrict__ sorig, int* __restrict__ knn_s,
    int* __restrict__ cnt, int* __restrict__ rev, int N, int BN) {
  int gang = (blockIdx.x * blockDim.x + threadIdx.x) >> 3;
  int sub = threadIdx.x & 7;
  if (gang >= BN) return;
  int b = gang / N;
  float2 cn = scoord[gang];
  float sqn = __fmaf_rn(cn.y, cn.y, __fmul_rn(cn.x, cn.x));
  int cx = (int)(cn.x * GRID); cx = cx < 0 ? 0 : (cx > GRID - 1 ? GRID - 1 : cx);
  int cy = (int)(cn.y * GRID); cy = cy < 0 ? 0 : (cy > GRID - 1 ? GRID - 1 : cy);
  const int* cs = cell_start + (size_t)b * (NCELL + 1);
  const float2* sc = scoord + (size_t)b * N;
  const int* so = sorig + (size_t)b * N;

  u64 list[KNN + 1];
#pragma unroll
  for (int j = 0; j <= KNN; ++j) list[j] = ~0ull;

  auto scan_cell = [&](int ux, int uy) {
    int c = uy * GRID + ux;
    int s = cs[c], e = cs[c + 1];
    for (int p = s + sub; p < e; p += 8) {
      float2 cm = sc[p];
      float sqm = __fmaf_rn(cm.y, cm.y, __fmul_rn(cm.x, cm.x));
      float dot = __fmaf_rn(cn.y, cm.y, __fmul_rn(cn.x, cm.x));
      float d2 = __fsub_rn(__fadd_rn(sqn, sqm), __fmul_rn(2.0f, dot));
      unsigned ub = __float_as_uint(d2);
      unsigned k32 = (ub & 0x80000000u) ? ~ub : (ub | 0x80000000u);
      u64 key = ((u64)k32 << 24) | ((u64)(unsigned)so[p] << 12) | (u64)(unsigned)p;
      if (key < list[KNN]) {
        u64 cur = key;
#pragma unroll
        for (int j = 0; j <= KNN; ++j) {
          u64 lo = list[j] < cur ? list[j] : cur;
          u64 hi = list[j] < cur ? cur : list[j];
          list[j] = lo;
          cur = hi;
        }
      }
    }
  };

  for (int q = 0; q <= GRID; ++q) {
    if (q == 0) {
      scan_cell(cx, cy);
    } else {
      int x0 = cx - q, x1 = cx + q, y0 = cy - q, y1 = cy + q;
      int xa = x0 < 0 ? 0 : x0, xb_ = x1 > GRID - 1 ? GRID - 1 : x1;
      for (int ux = xa; ux <= xb_; ++ux) {
        if (y0 >= 0) scan_cell(ux, y0);
        if (y1 <= GRID - 1) scan_cell(ux, y1);
      }
      int ya = (y0 + 1) < 0 ? 0 : y0 + 1, yb = (y1 - 1) > GRID - 1 ? GRID - 1 : y1 - 1;
      for (int uy = ya; uy <= yb; ++uy) {
        if (x0 >= 0) scan_cell(x0, uy);
        if (x1 <= GRID - 1) scan_cell(x1, uy);
      }
      float bound = (float)q * (1.0f / GRID);
      float thr = bound * bound - 1e-5f;
      int cntn = 0;
#pragma unroll
      for (int j = 0; j <= KNN; ++j) {
        unsigned k32 = (unsigned)(list[j] >> 24);
        float d2v = (k32 >= 0x80000000u) ? __uint_as_float(k32 & 0x7FFFFFFFu)
                                         : -__uint_as_float(~k32);
        cntn += (list[j] != ~0ull && d2v < thr) ? 1 : 0;
      }
#pragma unroll
      for (int o = 1; o < 8; o <<= 1) cntn += __shfl_xor(cntn, o, 64);
      if (cntn >= 9) break;
    }
  }

  int gl = gang - b * N;
  for (int r = 0; r <= KNN; ++r) {
    u64 cand = list[0];
    u64 mn = cand;
#pragma unroll
    for (int o = 1; o < 8; o <<= 1) {
      u64 v = __shfl_xor(mn, o, 64);
      mn = v < mn ? v : mn;
    }
    if (cand == mn) {
#pragma unroll
      for (int j = 0; j < KNN; ++j) list[j] = list[j + 1];
      list[KNN] = ~0ull;
      if (r > 0) {
        int m = (int)(mn & 0xFFFull);
        knn_s[(size_t)gang * KNN + (r - 1)] = m;
        int gm = b * N + m;
        int pos = atomicAdd(&cnt[gm], 1);
        if (pos < CAP) rev[(size_t)gm * CAP + pos] = gl;
      }
    }
  }
}

// ---------------------------------------------------------------------------
// Prep: blocks [0, 192) = W transpose+bf16 (Wt[l][n][k]); rest = nf -> bf16
// permuted to sorted order (2 rows per 256-thread block).
// ---------------------------------------------------------------------------
__global__ __launch_bounds__(256) void prep_kernel(
    const float* __restrict__ W, unsigned short* __restrict__ Wt,
    const float* __restrict__ nf, const int* __restrict__ sorig,
    unsigned short* __restrict__ xs, int N) {
  int bid = blockIdx.x;
  int t = threadIdx.x;
  if (bid < NLAYERS * 64) {
    __shared__ unsigned short tile[64][65];
    int l = bid >> 6;
    int t6 = bid & 63;
    int k0 = (t6 >> 3) * 64, n0 = (t6 & 7) * 64;
    const float* Wl = W + (size_t)l * HIDDEN * HIDDEN;
    unsigned short* Wtl = Wt + (size_t)l * HIDDEN * HIDDEN;
#pragma unroll
    for (int r = 0; r < 4; ++r) {
      int row = (t >> 4) + r * 16;
      int col = (t & 15) * 4;
      float4 v = *(const float4*)(Wl + (size_t)(k0 + row) * HIDDEN + n0 + col);
      tile[col + 0][row] = f2bf(v.x);
      tile[col + 1][row] = f2bf(v.y);
      tile[col + 2][row] = f2bf(v.z);
      tile[col + 3][row] = f2bf(v.w);
    }
    __syncthreads();
#pragma unroll
    for (int r = 0; r < 4; ++r) {
      int row = (t >> 4) + r * 16;
      int col = (t & 15) * 4;
      ushort4 o;
      o.x = tile[row][col + 0]; o.y = tile[row][col + 1];
      o.z = tile[row][col + 2]; o.w = tile[row][col + 3];
      *(ushort4*)(Wtl + (size_t)(n0 + row) * HIDDEN + k0 + col) = o;
    }
  } else {
    int row = (bid - NLAYERS * 64) * 2 + (t >> 7);
    int b = row / N;
    int src = b * N + sorig[row];
    int c = t & 127;
    float4 v = ((const float4*)(nf + (size_t)src * HIDDEN))[c];
    ushort4 o;
    o.x = f2bf(v.x); o.y = f2bf(v.y); o.z = f2bf(v.z); o.w = f2bf(v.w);
    ((ushort4*)(xs + (size_t)row * HIDDEN))[c] = o;
  }
}

// ---------------------------------------------------------------------------
// FUSED LAYER: agg(gather) + GEMM + bias + LN + ReLU + residual + store.
// Block = 32 rows x 512 cols, 256 threads = 4 waves (wave w owns cols
// [128w,128w+128)). Per wave: 2x8 MFMA 16x16x32 tiles (64 acc VGPRs).
// K-loop: waves 0-1 gather-accumulate A rows from xs (neighbor lists cached
// in LDS, bf16-rounded like the old aggb); waves 2-3 DMA W K-slice via
// global_load_lds. Epilogue: LDS cross-wave LN reduce; residual + outputs
// staged through Bs for coalesced global traffic. xs ping-pongs across layers.
// ---------------------------------------------------------------------------
__global__ __launch_bounds__(256) void layer_fused_kernel(
    const unsigned short* __restrict__ xs_cur,
    const int* __restrict__ knn_s, const int* __restrict__ cnt,
    const int* __restrict__ rev,
    const unsigned short* __restrict__ Wt, const float* __restrict__ bias,
    const float* __restrict__ g, const float* __restrict__ be,
    unsigned short* __restrict__ xs_next, float* __restrict__ out,
    const int* __restrict__ sorig, int N, int addres, int final_) {
  __shared__ unsigned short As[32 * 32];    // 2 KB [row][k]
  __shared__ unsigned short Bs[512 * 32];   // 32 KB [n][k]; reused in epilogue
  __shared__ unsigned short nlist[32 * 80]; // dedup'd neighbor lists
  __shared__ int ncnt[32];
  __shared__ float red[4][32][2];

  int t = threadIdx.x;
  int m0 = blockIdx.x * 32;   // global sorted row base (block within one batch)
  int b = m0 / N;
  int w = t >> 6, lane = t & 63, lm = lane & 15, q = lane >> 4;
  const unsigned short* xb = xs_cur + (size_t)b * N * HIDDEN;

  // ---- neighbor lists: 8 knn + dedup'd rev, into LDS
  {
    int row = t >> 3, slot = t & 7;
    nlist[row * 80 + slot] = (unsigned short)knn_s[(size_t)(m0 + row) * KNN + slot];
    if (slot == 0) ncnt[row] = KNN;
  }
  __syncthreads();
  {
    int row = t >> 3, slot = t & 7;
    int gm = m0 + row;
    int indeg = cnt[gm]; if (indeg > CAP) indeg = CAP;
    for (int e = slot; e < indeg; e += 8) {
      int rn = rev[(size_t)gm * CAP + e];
      bool dup = false;
#pragma unroll
      for (int j2 = 0; j2 < KNN; ++j2) dup = dup || (rn == (int)nlist[row * 80 + j2]);
      if (!dup) {
        int p = atomicAdd(&ncnt[row], 1);
        nlist[row * 80 + p] = (unsigned short)rn;
      }
    }
  }
  __syncthreads();

  f32x4 acc[2][8];
#pragma unroll
  for (int i = 0; i < 2; ++i)
#pragma unroll
    for (int j = 0; j < 8; ++j) acc[i][j] = (f32x4){0.f, 0.f, 0.f, 0.f};

  int arow = t >> 2;            // waves 0-1: row 0..31
  int aslice = (t & 3) * 8;     // k-slice 0,8,16,24
  int wb = (w - 2) * 16;        // waves 2-3: 16 chunks of 16 W-rows each
  int wrow = lane >> 2, wcol = (lane & 3) * 8;

  for (int k0 = 0; k0 < HIDDEN; k0 += 32) {
    __syncthreads();  // prior-iter LDS reads done before overwrite
    if (w < 2) {
      float a8[8] = {0.f, 0.f, 0.f, 0.f, 0.f, 0.f, 0.f, 0.f};
      int cr = ncnt[arow];
      const unsigned short* nl = nlist + arow * 80;
      auto addv = [&](uint4 v) {
        a8[0] += bf2f((unsigned short)(v.x & 0xFFFFu)); a8[1] += bf2f((unsigned short)(v.x >> 16));
        a8[2] += bf2f((unsigned short)(v.y & 0xFFFFu)); a8[3] += bf2f((unsigned short)(v.y >> 16));
        a8[4] += bf2f((unsigned short)(v.z & 0xFFFFu)); a8[5] += bf2f((unsigned short)(v.z >> 16));
        a8[6] += bf2f((unsigned short)(v.w & 0xFFFFu)); a8[7] += bf2f((unsigned short)(v.w >> 16));
      };
      int e = 0;
      for (; e + 4 <= cr; e += 4) {
        int n0 = nl[e], n1 = nl[e + 1], n2 = nl[e + 2], n3 = nl[e + 3];
        uint4 v0 = *(const uint4*)(xb + (size_t)n0 * HIDDEN + k0 + aslice);
        uint4 v1 = *(const uint4*)(xb + (size_t)n1 * HIDDEN + k0 + aslice);
        uint4 v2 = *(const uint4*)(xb + (size_t)n2 * HIDDEN + k0 + aslice);
        uint4 v3 = *(const uint4*)(xb + (size_t)n3 * HIDDEN + k0 + aslice);
        addv(v0); addv(v1); addv(v2); addv(v3);
      }
      for (; e < cr; ++e) {
        int nn = nl[e];
        uint4 v = *(const uint4*)(xb + (size_t)nn * HIDDEN + k0 + aslice);
        addv(v);
      }
      uint4 pk;
      pk.x = (unsigned)f2bf(a8[0]) | ((unsigned)f2bf(a8[1]) << 16);
      pk.y = (unsigned)f2bf(a8[2]) | ((unsigned)f2bf(a8[3]) << 16);
      pk.z = (unsigned)f2bf(a8[4]) | ((unsigned)f2bf(a8[5]) << 16);
      pk.w = (unsigned)f2bf(a8[6]) | ((unsigned)f2bf(a8[7]) << 16);
      *(uint4*)(As + arow * 32 + aslice) = pk;
    } else {
      const unsigned short* Wb = Wt + (size_t)(wb * 16 + wrow) * HIDDEN + k0 + wcol;
#pragma unroll
      for (int c = 0; c < 16; ++c)
        GLL16(Wb + (size_t)c * 16 * HIDDEN, Bs + (wb + c) * 16 * 32);
    }
    __syncthreads();
    short8 af0 = *(const short8*)(As + (lm) * 32 + q * 8);
    short8 af1 = *(const short8*)(As + (16 + lm) * 32 + q * 8);
#pragma unroll
    for (int j = 0; j < 8; ++j) {
      short8 bf8 = *(const short8*)(Bs + (w * 128 + j * 16 + lm) * 32 + q * 8);
      acc[0][j] = __builtin_amdgcn_mfma_f32_16x16x32_bf16(af0, bf8, acc[0][j], 0, 0, 0);
      acc[1][j] = __builtin_amdgcn_mfma_f32_16x16x32_bf16(af1, bf8, acc[1][j], 0, 0, 0);
    }
  }

  // ---- epilogue: bias + LN stats
  float bj[8], gj[8], bej[8];
#pragma unroll
  for (int j = 0; j < 8; ++j) {
    int col = w * 128 + j * 16 + lm;
    bj[j] = bias[col]; gj[j] = g[col]; bej[j] = be[col];
  }
  float s[2][4], ss[2][4];
#pragma unroll
  for (int i = 0; i < 2; ++i)
#pragma unroll
    for (int r = 0; r < 4; ++r) { s[i][r] = 0.f; ss[i][r] = 0.f; }
#pragma unroll
  for (int i = 0; i < 2; ++i)
#pragma unroll
    for (int j = 0; j < 8; ++j)
#pragma unroll
      for (int r = 0; r < 4; ++r) {
        float v = acc[i][j][r] + bj[j];
        acc[i][j][r] = v;
        s[i][r] += v;
        ss[i][r] += v * v;
      }
#pragma unroll
  for (int i = 0; i < 2; ++i)
#pragma unroll
    for (int r = 0; r < 4; ++r) {
#pragma unroll
      for (int o = 1; o < 16; o <<= 1) {
        s[i][r] += __shfl_xor(s[i][r], o, 64);
        ss[i][r] += __shfl_xor(ss[i][r], o, 64);
      }
    }
  if (lm == 0) {
#pragma unroll
    for (int i = 0; i < 2; ++i)
#pragma unroll
      for (int r = 0; r < 4; ++r) {
        int rl = i * 16 + q * 4 + r;
        red[w][rl][0] = s[i][r];
        red[w][rl][1] = ss[i][r];
      }
  }
  __syncthreads();  // red ready; also: all MFMA LDS reads done -> Bs reusable

  float mu[2][4], inv[2][4];
#pragma unroll
  for (int i = 0; i < 2; ++i)
#pragma unroll
    for (int r = 0; r < 4; ++r) {
      int rl = i * 16 + q * 4 + r;
      float S = red[0][rl][0] + red[1][rl][0] + red[2][rl][0] + red[3][rl][0];
      float SS = red[0][rl][1] + red[1][rl][1] + red[2][rl][1] + red[3][rl][1];
      float m = S * (1.0f / HIDDEN);
      mu[i][r] = m;
      inv[i][r] = rsqrtf(SS * (1.0f / HIDDEN) - m * m + EPSV);
    }

  if (!final_) {
    unsigned short* ym = Bs;  // reuse as u16[32][512]
    if (addres) {
#pragma unroll
      for (int it = 0; it < 8; ++it) {
        int u = it * 256 + t;
        int row = u >> 6, c = u & 63;
        *(uint4*)(ym + row * 512 + c * 8) =
            *(const uint4*)(xs_cur + (size_t)(m0 + row) * HIDDEN + c * 8);
      }
    }
    __syncthreads();
#pragma unroll
    for (int i = 0; i < 2; ++i)
#pragma unroll
      for (int j = 0; j < 8; ++j)
#pragma unroll
        for (int r = 0; r < 4; ++r) {
          int row = i * 16 + q * 4 + r;
          int col = w * 128 + j * 16 + lm;
          float v = fmaxf((acc[i][j][r] - mu[i][r]) * inv[i][r] * gj[j] + bej[j], 0.f);
          if (addres) v += bf2f(ym[row * 512 + col]);
          ym[row * 512 + col] = f2bf(v);  // own cell: read-then-write safe
        }
    __syncthreads();
#pragma unroll
    for (int it = 0; it < 8; ++it) {
      int u = it * 256 + t;
      int row = u >> 6, c = u & 63;
      *(uint4*)(xs_next + (size_t)(m0 + row) * HIDDEN + c * 8) =
          *(const uint4*)(ym + row * 512 + c * 8);
    }
  } else {
    float* om = (float*)Bs;  // reuse as f32[16][512]
    for (int grp = 0; grp < 2; ++grp) {
      __syncthreads();
      int i = grp;
#pragma unroll
      for (int j = 0; j < 8; ++j)
#pragma unroll
        for (int r = 0; r < 4; ++r) {
          int rowl = q * 4 + r;
          int row = i * 16 + rowl;
          int col = w * 128 + j * 16 + lm;
          float v = fmaxf((acc[i][j][r] - mu[i][r]) * inv[i][r] * gj[j] + bej[j], 0.f);
          v += bf2f(xs_cur[(size_t)(m0 + row) * HIDDEN + col]);  // residual (L3-warm)
          om[rowl * 512 + col] = v;
        }
      __syncthreads();
#pragma unroll
      for (int it = 0; it < 8; ++it) {
        int u = it * 256 + t;
        int rowl = u >> 7, c = u & 127;
        int dstrow = b * N + sorig[m0 + grp * 16 + rowl];
        *(uint4*)(out + (size_t)dstrow * HIDDEN + c * 4) =
            *(const uint4*)(om + rowl * 512 + c * 4);
      }
    }
  }
}

// ---------------------------------------------------------------------------
extern "C" void kernel_launch(void* const* d_in, const int* in_sizes, int n_in,
                              void* d_out, int out_size, void* d_ws, size_t ws_size,
                              hipStream_t stream) {
  const float* nf = (const float*)d_in[0];
  const float2* coords = (const float2*)d_in[1];
  const float* Wall = (const float*)d_in[2];
  const float* ball = (const float*)d_in[3];
  const float* gall = (const float*)d_in[4];
  const float* beall = (const float*)d_in[5];
  float* out = (float*)d_out;

  int BN = in_sizes[0] / HIDDEN;  // 16384
  int N = 4096;
  int B = BN / N;

  char* ws = (char*)d_ws;
  size_t off = 0;
  auto alloc = [&](size_t bytes) -> void* {
    off = (off + 255) & ~(size_t)255;
    void* p = ws + off;
    off += bytes;
    return p;
  };
  int* knn_s = (int*)alloc((size_t)BN * KNN * sizeof(int));
  int* cnt = (int*)alloc((size_t)BN * sizeof(int));
  int* rev = (int*)alloc((size_t)BN * CAP * sizeof(int));
  unsigned short* Wt = (unsigned short*)alloc((size_t)NLAYERS * HIDDEN * HIDDEN * sizeof(unsigned short));
  unsigned short* xs0 = (unsigned short*)alloc((size_t)BN * HIDDEN * sizeof(unsigned short));
  unsigned short* xs1 = (unsigned short*)alloc((size_t)BN * HIDDEN * sizeof(unsigned short));
  int* cell_start = (int*)alloc((size_t)B * (NCELL + 1) * sizeof(int));
  float2* scoord = (float2*)alloc((size_t)BN * sizeof(float2));
  int* sorig = (int*)alloc((size_t)BN * sizeof(int));

  hipMemsetAsync(cnt, 0, (size_t)BN * sizeof(int), stream);
  grid_build_kernel<<<B, 1024, 0, stream>>>(coords, cell_start, scoord, sorig, N);
  knn_grid_kernel<<<(BN * 8 + 255) / 256, 256, 0, stream>>>(cell_start, scoord, sorig, knn_s, cnt, rev, N, BN);
  prep_kernel<<<NLAYERS * 64 + BN / 2, 256, 0, stream>>>(Wall, Wt, nf, sorig, xs0, N);

  // layer 0: xs0 -> xs1 (no residual); layer 1: xs1 -> xs0 (+res);
  // layer 2: xs0 -> out scatter (+res)
  layer_fused_kernel<<<BN / 32, 256, 0, stream>>>(
      xs0, knn_s, cnt, rev, Wt, ball, gall, beall, xs1, out, sorig, N, 0, 0);
  layer_fused_kernel<<<BN / 32, 256, 0, stream>>>(
      xs1, knn_s, cnt, rev, Wt + (size_t)HIDDEN * HIDDEN, ball + HIDDEN,
      gall + HIDDEN, beall + HIDDEN, xs0, out, sorig, N, 1, 0);
  layer_fused_kernel<<<BN / 32, 256, 0, stream>>>(
      xs0, knn_s, cnt, rev, Wt + (size_t)2 * HIDDEN * HIDDEN, ball + 2 * HIDDEN,
      gall + 2 * HIDDEN, beall + 2 * HIDDEN, xs1, out, sorig, N, 1, 1);
}